// Round 2
// baseline (138.838 us; speedup 1.0000x reference)
//
#include <hip/hip_runtime.h>

#define T_LEN 1024
#define R_N   196
#define H_N   512
#define EBD_N 512
#define C_N   512

// tanh(x) = 1 - 2/(exp(2x)+1); rcp approx is plenty for the ~2e-3 threshold.
// exp overflow -> inf -> rcp -> 0 -> 1; underflow -> 0 -> -1. Saturates safely.
__device__ inline float fast_tanh(float x){
  float e = __expf(x + x);
  return 1.f - 2.f * __builtin_amdgcn_rcpf(e + 1.f);
}

// ---------------- K1a/K1b: Y[r][e] = relu?( X[r][:] . W[e][:] + bias[e] )
// grid(49, 2): 4 regions per block, 256 e per block-column. block 256.
#define RB 4
__global__ __launch_bounds__(256) void k_rowgemm(
    const float* __restrict__ X, const float* __restrict__ W,
    const float* __restrict__ bias, float* __restrict__ Y, int relu){
  __shared__ float F[RB][C_N];
  const int r0 = blockIdx.x * RB, tid = threadIdx.x;
  for (int i = tid; i < RB*C_N/4; i += 256)
    reinterpret_cast<float4*>(&F[0][0])[i] =
        reinterpret_cast<const float4*>(X + (size_t)r0*C_N)[i];
  __syncthreads();

  const int e = blockIdx.y * 256 + tid;
  const float4* w4 = reinterpret_cast<const float4*>(W + (size_t)e*C_N);
  const float bb = bias ? bias[e] : 0.f;
  float acc[RB] = {bb, bb, bb, bb};
  for (int c4 = 0; c4 < C_N/4; ++c4){
    float4 w = w4[c4];
    #pragma unroll
    for (int rr = 0; rr < RB; ++rr){
      float4 f = reinterpret_cast<const float4*>(F[rr])[c4];
      acc[rr] += w.x*f.x + w.y*f.y + w.z*f.z + w.w*f.w;
    }
  }
  #pragma unroll
  for (int rr = 0; rr < RB; ++rr){
    float v = relu ? fmaxf(acc[rr], 0.f) : acc[rr];
    Y[(size_t)(r0+rr)*EBD_N + e] = v;
  }
}

// ---------------- K2: E = emb[question]; out[:,512:] = E; AW = E @ W_aw^T + b_aw
// grid(128, 2): 8 tokens per block, 256 h per block-column. block 256.
#define TB2 8
__global__ __launch_bounds__(256) void k_aw_emb(
    const int* __restrict__ question, const float* __restrict__ emb,
    const float* __restrict__ W_aw,   const float* __restrict__ b_aw,
    float* __restrict__ AW, float* __restrict__ out){
  __shared__ float E[TB2][EBD_N];
  const int t0 = blockIdx.x * TB2, tid = threadIdx.x;
  for (int i = tid; i < TB2*(EBD_N/4); i += 256){
    const int tt = i / (EBD_N/4), ci = i % (EBD_N/4);
    const int q = question[t0 + tt];
    float4 v = reinterpret_cast<const float4*>(emb + (size_t)q*EBD_N)[ci];
    reinterpret_cast<float4*>(E[tt])[ci] = v;
    if (blockIdx.y == 0)
      reinterpret_cast<float4*>(out + (size_t)(t0+tt)*1024 + 512)[ci] = v;
  }
  __syncthreads();

  const int h = blockIdx.y * 256 + tid;
  const float4* w4 = reinterpret_cast<const float4*>(W_aw + (size_t)h*EBD_N);
  const float bb = b_aw[h];
  float acc[TB2];
  #pragma unroll
  for (int tt = 0; tt < TB2; ++tt) acc[tt] = bb;
  for (int c4 = 0; c4 < EBD_N/4; ++c4){
    float4 w = w4[c4];
    #pragma unroll
    for (int tt = 0; tt < TB2; ++tt){
      float4 f = reinterpret_cast<const float4*>(E[tt])[c4];
      acc[tt] += w.x*f.x + w.y*f.y + w.z*f.z + w.w*f.w;
    }
  }
  #pragma unroll
  for (int tt = 0; tt < TB2; ++tt)
    AW[(size_t)(t0+tt)*H_N + h] = acc[tt];
}

// ---------------- K3: scores -> softmax -> ctx. 4 tokens per block, 256 blocks.
#define TB3 4
__global__ __launch_bounds__(256) void k_att(
    const float* __restrict__ AI, const float* __restrict__ AW,
    const float* __restrict__ img, const float* __restrict__ w_att,
    float* __restrict__ out){
  __shared__ float wgt[TB3][R_N];
  const int t0 = blockIdx.x * TB3, tid = threadIdx.x;
  const int wave = tid >> 6, lane = tid & 63;
  const int hb = lane * 8;

  // per-lane hoisted operands, fixed across r
  float wv[8], aw[TB3][8];
  {
    float4 a = reinterpret_cast<const float4*>(w_att + hb)[0];
    float4 b = reinterpret_cast<const float4*>(w_att + hb)[1];
    wv[0]=a.x; wv[1]=a.y; wv[2]=a.z; wv[3]=a.w;
    wv[4]=b.x; wv[5]=b.y; wv[6]=b.z; wv[7]=b.w;
    #pragma unroll
    for (int tt = 0; tt < TB3; ++tt){
      const float* p = AW + (size_t)(t0+tt)*H_N + hb;
      float4 c = reinterpret_cast<const float4*>(p)[0];
      float4 d = reinterpret_cast<const float4*>(p)[1];
      aw[tt][0]=c.x; aw[tt][1]=c.y; aw[tt][2]=c.z; aw[tt][3]=c.w;
      aw[tt][4]=d.x; aw[tt][5]=d.y; aw[tt][6]=d.z; aw[tt][7]=d.w;
    }
  }

  // scores: wave handles r = wave, wave+4, ...
  for (int r = wave; r < R_N; r += 4){
    const float* p = AI + (size_t)r*H_N + hb;
    float4 a = reinterpret_cast<const float4*>(p)[0];
    float4 b = reinterpret_cast<const float4*>(p)[1];
    float ai[8] = {a.x,a.y,a.z,a.w,b.x,b.y,b.z,b.w};
    float acc[TB3] = {0.f,0.f,0.f,0.f};
    #pragma unroll
    for (int j = 0; j < 8; ++j){
      #pragma unroll
      for (int tt = 0; tt < TB3; ++tt)
        acc[tt] += fast_tanh(ai[j] + aw[tt][j]) * wv[j];
    }
    #pragma unroll
    for (int o = 32; o; o >>= 1){
      #pragma unroll
      for (int tt = 0; tt < TB3; ++tt)
        acc[tt] += __shfl_down(acc[tt], o, 64);
    }
    if (lane == 0){
      #pragma unroll
      for (int tt = 0; tt < TB3; ++tt) wgt[tt][r] = acc[tt];
    }
  }
  __syncthreads();

  // softmax over R for t = t0 + wave (4 waves = TB3); fold the /R_N here
  {
    float v[4]; float m = -1e30f;
    #pragma unroll
    for (int i = 0; i < 4; ++i){
      const int r = lane + 64*i;
      v[i] = (r < R_N) ? wgt[wave][r] : -1e30f;
      m = fmaxf(m, v[i]);
    }
    #pragma unroll
    for (int o = 32; o; o >>= 1) m = fmaxf(m, __shfl_xor(m, o, 64));
    float s = 0.f;
    #pragma unroll
    for (int i = 0; i < 4; ++i){
      const int r = lane + 64*i;
      if (r < R_N){ v[i] = __expf(v[i] - m); s += v[i]; }
    }
    #pragma unroll
    for (int o = 32; o; o >>= 1) s += __shfl_xor(s, o, 64);
    const float inv = 1.f / (s * (float)R_N);
    #pragma unroll
    for (int i = 0; i < 4; ++i){
      const int r = lane + 64*i;
      if (r < R_N) wgt[wave][r] = v[i] * inv;
    }
  }
  __syncthreads();

  // ctx: thread handles e = 2*tid, 2*tid+1 for all TB3 tokens
  {
    const int e = 2*tid;
    float a[TB3][2];
    #pragma unroll
    for (int tt = 0; tt < TB3; ++tt){ a[tt][0] = 0.f; a[tt][1] = 0.f; }
    for (int r = 0; r < R_N; ++r){
      float2 f = *reinterpret_cast<const float2*>(img + (size_t)r*EBD_N + e);
      #pragma unroll
      for (int tt = 0; tt < TB3; ++tt){
        const float w = wgt[tt][r];
        a[tt][0] += w * f.x; a[tt][1] += w * f.y;
      }
    }
    #pragma unroll
    for (int tt = 0; tt < TB3; ++tt){
      float2 o; o.x = a[tt][0]; o.y = a[tt][1];
      *reinterpret_cast<float2*>(out + (size_t)(t0+tt)*1024 + e) = o;
    }
  }
}

extern "C" void kernel_launch(void* const* d_in, const int* in_sizes, int n_in,
                              void* d_out, int out_size, void* d_ws, size_t ws_size,
                              hipStream_t stream) {
  const int*   question = (const int*)d_in[0];
  const float* img_feat = (const float*)d_in[1];
  const float* emb      = (const float*)d_in[2];
  const float* W_img    = (const float*)d_in[3];
  const float* b_img    = (const float*)d_in[4];
  const float* W_ai     = (const float*)d_in[5];
  const float* W_aw     = (const float*)d_in[6];
  const float* b_aw     = (const float*)d_in[7];
  const float* w_att    = (const float*)d_in[8];
  // d_in[9] = b_att: constant shift before softmax -> mathematically a no-op.
  float* out = (float*)d_out;

  char* ws = (char*)d_ws;
  float* img_b = (float*)ws;                  // 196*512*4 = 401408 B
  float* AI_b  = (float*)(ws + 401408);       // 196*512*4 = 401408 B
  float* AW    = (float*)(ws + 802816);       // 1024*512*4 = 2097152 B

  hipLaunchKernelGGL(k_rowgemm, dim3(R_N/RB, 2),     dim3(256), 0, stream,
                     img_feat, W_img, b_img, img_b, 1);
  hipLaunchKernelGGL(k_rowgemm, dim3(R_N/RB, 2),     dim3(256), 0, stream,
                     img_b, W_ai, (const float*)nullptr, AI_b, 0);
  hipLaunchKernelGGL(k_aw_emb,  dim3(T_LEN/TB2, 2),  dim3(256), 0, stream,
                     question, emb, W_aw, b_aw, AW, out);
  hipLaunchKernelGGL(k_att,     dim3(T_LEN/TB3),     dim3(256), 0, stream,
                     AI_b, AW, img_b, w_att, out);
}

// Round 3
// 112.842 us; speedup vs baseline: 1.2304x; 1.2304x over previous
//
#include <hip/hip_runtime.h>

#define T_LEN 1024
#define R_N   196
#define H_N   512
#define SPAD  200   // padded score row (16B multiple)
#define APAD  208   // padded AI_T row (196 -> 208, 16B multiple)
#define PRESCALE 2.8853900817779268f   // 2*log2(e): exp2(PRESCALE*x) = e^{2x}

// ---------------- transpose 512x512 f32 (LDS tile, conflict-free pad 65)
__global__ __launch_bounds__(256) void k_trans(
    const float* __restrict__ src, float* __restrict__ dst){
  __shared__ float T[64*65];
  const int r0 = blockIdx.x*64, c0 = blockIdx.y*64, tid = threadIdx.x;
  #pragma unroll
  for (int p = 0; p < 4; ++p){
    const int rr = (tid>>4) + p*16, cq = (tid&15)*4;
    float4 v = *reinterpret_cast<const float4*>(src + (size_t)(r0+rr)*512 + c0 + cq);
    T[rr*65+cq] = v.x; T[rr*65+cq+1] = v.y; T[rr*65+cq+2] = v.z; T[rr*65+cq+3] = v.w;
  }
  __syncthreads();
  #pragma unroll
  for (int p = 0; p < 4; ++p){
    const int cc = (tid>>4) + p*16, rq = (tid&15)*4;
    float4 v;
    v.x = T[(rq+0)*65+cc]; v.y = T[(rq+1)*65+cc];
    v.z = T[(rq+2)*65+cc]; v.w = T[(rq+3)*65+cc];
    *reinterpret_cast<float4*>(dst + (size_t)(c0+cc)*512 + r0 + rq) = v;
  }
}

// ---------------- img = relu(img_feat @ W_imgT + b). grid(49,8), 256 thr.
// 4 rows/block staged in LDS; lane<->e coalesced W_T loads; waves split K.
__global__ __launch_bounds__(256) void k_gemm_img(
    const float* __restrict__ X, const float* __restrict__ WT,
    const float* __restrict__ bias, float* __restrict__ Y){
  __shared__ float Xs[4][512];
  __shared__ float part[4][4][64];
  const int tid = threadIdx.x, w = tid>>6, lane = tid&63;
  const int r0 = blockIdx.x*4, e = blockIdx.y*64 + lane;
  for (int i = tid; i < 4*128; i += 256)
    reinterpret_cast<float4*>(Xs[i>>7])[i&127] =
      reinterpret_cast<const float4*>(X + (size_t)(r0+(i>>7))*512)[i&127];
  __syncthreads();
  float acc[4] = {0,0,0,0};
  const float* wp = WT + (size_t)(w*128)*512 + blockIdx.y*64 + lane;
  #pragma unroll 2
  for (int c = 0; c < 128; c += 4){
    float w0 = wp[0], w1 = wp[512], w2 = wp[1024], w3 = wp[1536];
    wp += 2048;
    #pragma unroll
    for (int rr = 0; rr < 4; ++rr){
      float4 x = *reinterpret_cast<const float4*>(&Xs[rr][w*128+c]);
      acc[rr] += x.x*w0 + x.y*w1 + x.z*w2 + x.w*w3;
    }
  }
  #pragma unroll
  for (int rr = 0; rr < 4; ++rr) part[w][rr][lane] = acc[rr];
  __syncthreads();
  const int rr = tid>>6;
  float v = part[0][rr][lane]+part[1][rr][lane]+part[2][rr][lane]+part[3][rr][lane];
  v = fmaxf(v + bias[e], 0.f);
  Y[(size_t)(r0+rr)*512 + e] = v;
}

// ---------------- AI_T[h][r] = PRESCALE * (img @ W_aiT)[r][h]. grid(49,8).
__global__ __launch_bounds__(256) void k_gemm_ai(
    const float* __restrict__ X, const float* __restrict__ WT,
    float* __restrict__ AIT){
  __shared__ float Xs[4][512];
  __shared__ float part[4][4][64];
  const int tid = threadIdx.x, w = tid>>6, lane = tid&63;
  const int r0 = blockIdx.x*4;
  for (int i = tid; i < 4*128; i += 256)
    reinterpret_cast<float4*>(Xs[i>>7])[i&127] =
      reinterpret_cast<const float4*>(X + (size_t)(r0+(i>>7))*512)[i&127];
  __syncthreads();
  float acc[4] = {0,0,0,0};
  const float* wp = WT + (size_t)(w*128)*512 + blockIdx.y*64 + lane;
  #pragma unroll 2
  for (int c = 0; c < 128; c += 4){
    float w0 = wp[0], w1 = wp[512], w2 = wp[1024], w3 = wp[1536];
    wp += 2048;
    #pragma unroll
    for (int rr = 0; rr < 4; ++rr){
      float4 x = *reinterpret_cast<const float4*>(&Xs[rr][w*128+c]);
      acc[rr] += x.x*w0 + x.y*w1 + x.z*w2 + x.w*w3;
    }
  }
  #pragma unroll
  for (int rr = 0; rr < 4; ++rr) part[w][rr][lane] = acc[rr];
  __syncthreads();
  const int rr = tid>>6;
  float v = (part[0][rr][lane]+part[1][rr][lane]+part[2][rr][lane]+part[3][rr][lane]) * PRESCALE;
  AIT[(size_t)(blockIdx.y*64+lane)*APAD + r0 + rr] = v;   // transposed scatter (small)
}

// ---------------- AW' = PRESCALE*(E @ W_awT + b); also out[:,512:] = E.
// grid(128,8), 256 thr, 8 tokens/block.
__global__ __launch_bounds__(256) void k_gemm_aw(
    const int* __restrict__ question, const float* __restrict__ emb,
    const float* __restrict__ WT, const float* __restrict__ bias,
    float* __restrict__ AW, float* __restrict__ out){
  __shared__ float Es[8][512];
  __shared__ float part[4][8][64];
  const int tid = threadIdx.x, w = tid>>6, lane = tid&63;
  const int t0 = blockIdx.x*8, hb = blockIdx.y*64;
  {
    const int m = tid>>5, cb = tid&31;
    const float* er = emb + (size_t)question[t0+m]*512;
    float* orow = out + (size_t)(t0+m)*1024 + 512;
    #pragma unroll
    for (int p = 0; p < 4; ++p){
      const int cq = cb + p*32;
      float4 v = reinterpret_cast<const float4*>(er)[cq];
      reinterpret_cast<float4*>(Es[m])[cq] = v;
      if (blockIdx.y == 0) reinterpret_cast<float4*>(orow)[cq] = v;
    }
  }
  __syncthreads();
  float acc[8] = {0,0,0,0,0,0,0,0};
  const float* wp = WT + (size_t)(w*128)*512 + hb + lane;
  for (int c = 0; c < 128; c += 4){
    float w0 = wp[0], w1 = wp[512], w2 = wp[1024], w3 = wp[1536];
    wp += 2048;
    #pragma unroll
    for (int m = 0; m < 8; ++m){
      float4 x = *reinterpret_cast<const float4*>(&Es[m][w*128+c]);
      acc[m] += x.x*w0 + x.y*w1 + x.z*w2 + x.w*w3;
    }
  }
  #pragma unroll
  for (int m = 0; m < 8; ++m) part[w][m][lane] = acc[m];
  __syncthreads();
  const int m0 = tid>>6;
  #pragma unroll
  for (int k = 0; k < 2; ++k){
    const int m = m0 + k*4;
    float v = part[0][m][lane]+part[1][m][lane]+part[2][m][lane]+part[3][m][lane];
    v = (v + bias[hb+lane]) * PRESCALE;
    AW[(size_t)(t0+m)*512 + hb + lane] = v;
  }
}

// ---------------- S[t][r] = sum_h w[h] * rcp(exp2(AI'[h][r]+AW'[t][h]) + 1)
// softmax(score) == softmax(-2*S). grid(256,4): wave<->token, lane<->r.
__global__ __launch_bounds__(256) void k_score(
    const float* __restrict__ AIT, const float* __restrict__ AW,
    const float* __restrict__ w_att, float* __restrict__ S){
  __shared__ float AWs[4][512];
  __shared__ float Ws[512];
  const int tid = threadIdx.x, w = tid>>6, lane = tid&63;
  const int t0 = blockIdx.x*4, rb = blockIdx.y*49;
  for (int i = tid; i < 4*128; i += 256)
    reinterpret_cast<float4*>(AWs[i>>7])[i&127] =
      reinterpret_cast<const float4*>(AW + (size_t)(t0+(i>>7))*512)[i&127];
  for (int i = tid; i < 128; i += 256)
    reinterpret_cast<float4*>(Ws)[i] = reinterpret_cast<const float4*>(w_att)[i];
  __syncthreads();
  const bool act = lane < 49;
  const int r = rb + (act ? lane : 0);     // clamp idle lanes in-bounds
  const float* ap = AIT + r;               // AIT rows stride APAD
  float s = 0.f;
  #pragma unroll 2
  for (int h = 0; h < 512; h += 4){
    float a0 = ap[0], a1 = ap[APAD], a2 = ap[2*APAD], a3 = ap[3*APAD];
    ap += 4*APAD;
    float4 aw = *reinterpret_cast<const float4*>(&AWs[w][h]);   // broadcast
    float4 wv = *reinterpret_cast<const float4*>(&Ws[h]);       // broadcast
    float e0 = exp2f(a0 + aw.x), e1 = exp2f(a1 + aw.y);
    float e2 = exp2f(a2 + aw.z), e3 = exp2f(a3 + aw.w);
    s += wv.x*__builtin_amdgcn_rcpf(e0+1.f);
    s += wv.y*__builtin_amdgcn_rcpf(e1+1.f);
    s += wv.z*__builtin_amdgcn_rcpf(e2+1.f);
    s += wv.w*__builtin_amdgcn_rcpf(e3+1.f);
  }
  if (act) S[(size_t)(t0+w)*SPAD + rb + lane] = s;
}

// ---------------- softmax(-2S) (folding /196) then ctx = w @ img. grid 256, 512 thr.
__global__ __launch_bounds__(512) void k_ctx(
    const float* __restrict__ S, const float* __restrict__ img,
    float* __restrict__ out){
  __shared__ float wgt[R_N][4];    // [r][token], b128 broadcast in ctx loop
  const int tid = threadIdx.x, w = tid>>6, lane = tid&63;
  const int t0 = blockIdx.x*4;
  if (w < 4){
    const float* sr = S + (size_t)(t0+w)*SPAD;
    float v0 = sr[lane], v1 = sr[64+lane], v2 = sr[128+lane];
    float v3 = (lane < 4) ? sr[192+lane] : 1e30f;
    float m = fminf(fminf(v0,v1), fminf(v2,v3));     // max logit = -2*min S
    #pragma unroll
    for (int o = 32; o; o >>= 1) m = fminf(m, __shfl_xor(m, o, 64));
    float p0 = exp2f(PRESCALE*(m-v0)), p1 = exp2f(PRESCALE*(m-v1));
    float p2 = exp2f(PRESCALE*(m-v2));
    float p3 = (lane < 4) ? exp2f(PRESCALE*(m-v3)) : 0.f;
    float sum = p0+p1+p2+p3;
    #pragma unroll
    for (int o = 32; o; o >>= 1) sum += __shfl_xor(sum, o, 64);
    const float inv = 1.f/(sum*196.f);
    wgt[lane][w] = p0*inv; wgt[64+lane][w] = p1*inv; wgt[128+lane][w] = p2*inv;
    if (lane < 4) wgt[192+lane][w] = p3*inv;
  }
  __syncthreads();
  const int e = tid;
  float a0=0.f, a1=0.f, a2=0.f, a3=0.f;
  const float* ip = img + e;
  #pragma unroll 4
  for (int r = 0; r < R_N; ++r){
    float f = ip[0]; ip += 512;
    float4 ww = *reinterpret_cast<const float4*>(wgt[r]);
    a0 += ww.x*f; a1 += ww.y*f; a2 += ww.z*f; a3 += ww.w*f;
  }
  out[(size_t)(t0+0)*1024 + e] = a0;
  out[(size_t)(t0+1)*1024 + e] = a1;
  out[(size_t)(t0+2)*1024 + e] = a2;
  out[(size_t)(t0+3)*1024 + e] = a3;
}

extern "C" void kernel_launch(void* const* d_in, const int* in_sizes, int n_in,
                              void* d_out, int out_size, void* d_ws, size_t ws_size,
                              hipStream_t stream) {
  const int*   question = (const int*)d_in[0];
  const float* img_feat = (const float*)d_in[1];
  const float* emb      = (const float*)d_in[2];
  const float* W_img    = (const float*)d_in[3];
  const float* b_img    = (const float*)d_in[4];
  const float* W_ai     = (const float*)d_in[5];
  const float* W_aw     = (const float*)d_in[6];
  const float* b_aw     = (const float*)d_in[7];
  const float* w_att    = (const float*)d_in[8];
  // d_in[9] = b_att: constant pre-softmax shift -> cancels. Sum(w_att)*1 term also cancels.
  float* out = (float*)d_out;

  char* ws = (char*)d_ws;                       // total 4.58 MB, WT region reused 3x
  float* WT  = (float*)(ws);                    // 1 MB
  float* img = (float*)(ws + 1048576);          // 401408 B
  float* AIT = (float*)(ws + 1449984);          // 512*208*4 = 425984 B
  float* S   = (float*)(ws + 1875968);          // 1024*200*4 = 819200 B
  float* AW  = (float*)(ws + 2695168);          // 2 MB

  hipLaunchKernelGGL(k_trans,    dim3(8,8),    dim3(256), 0, stream, W_img, WT);
  hipLaunchKernelGGL(k_gemm_img, dim3(49,8),   dim3(256), 0, stream, img_feat, WT, b_img, img);
  hipLaunchKernelGGL(k_trans,    dim3(8,8),    dim3(256), 0, stream, W_ai, WT);
  hipLaunchKernelGGL(k_gemm_ai,  dim3(49,8),   dim3(256), 0, stream, img, WT, AIT);
  hipLaunchKernelGGL(k_trans,    dim3(8,8),    dim3(256), 0, stream, W_aw, WT);
  hipLaunchKernelGGL(k_gemm_aw,  dim3(128,8),  dim3(256), 0, stream, question, emb, WT, b_aw, AW, out);
  hipLaunchKernelGGL(k_score,    dim3(256,4),  dim3(256), 0, stream, AIT, AW, w_att, S);
  hipLaunchKernelGGL(k_ctx,      dim3(256),    dim3(512), 0, stream, S, img, out);
}

// Round 4
// 101.069 us; speedup vs baseline: 1.3737x; 1.1165x over previous
//
#include <hip/hip_runtime.h>

#define T_LEN 1024
#define R_N   196
#define H_N   512
#define PRESCALE 2.8853900817779268f   // 2*log2(e): exp2(PRESCALE*x) = e^{2x}

// Raw v_exp_f32 / v_rcp_f32 — OCML exp2f carries a denorm fixup (~3x ops).
// Args here are |z| < ~40, far from the denormal range: raw op is exact enough.
#if defined(__has_builtin)
#if __has_builtin(__builtin_amdgcn_exp2f)
#define EXP2(x) __builtin_amdgcn_exp2f(x)
#endif
#endif
#ifndef EXP2
#define EXP2(x) exp2f(x)
#endif
#define RCP(x) __builtin_amdgcn_rcpf(x)

// ---------------- fused transpose of the three 512x512 weights
__global__ __launch_bounds__(256) void k_trans3(
    const float* __restrict__ W0, const float* __restrict__ W1,
    const float* __restrict__ W2, float* __restrict__ WT3){
  __shared__ float T[64*65];
  const float* src = (blockIdx.z == 0) ? W0 : ((blockIdx.z == 1) ? W1 : W2);
  float* dst = WT3 + (size_t)blockIdx.z * (512*512);
  const int r0 = blockIdx.x*64, c0 = blockIdx.y*64, tid = threadIdx.x;
  #pragma unroll
  for (int p = 0; p < 4; ++p){
    const int rr = (tid>>4) + p*16, cq = (tid&15)*4;
    float4 v = *reinterpret_cast<const float4*>(src + (size_t)(r0+rr)*512 + c0 + cq);
    T[rr*65+cq] = v.x; T[rr*65+cq+1] = v.y; T[rr*65+cq+2] = v.z; T[rr*65+cq+3] = v.w;
  }
  __syncthreads();
  #pragma unroll
  for (int p = 0; p < 4; ++p){
    const int cc = (tid>>4) + p*16, rq = (tid&15)*4;
    float4 v;
    v.x = T[(rq+0)*65+cc]; v.y = T[(rq+1)*65+cc];
    v.z = T[(rq+2)*65+cc]; v.w = T[(rq+3)*65+cc];
    *reinterpret_cast<float4*>(dst + (size_t)(c0+cc)*512 + r0 + rq) = v;
  }
}

// ---------------- img = relu(img_feat @ W_imgT + b). grid(49,8), 256 thr.
__global__ __launch_bounds__(256) void k_gemm_img(
    const float* __restrict__ X, const float* __restrict__ WT,
    const float* __restrict__ bias, float* __restrict__ Y){
  __shared__ float Xs[4][512];
  __shared__ float part[4][4][64];
  const int tid = threadIdx.x, w = tid>>6, lane = tid&63;
  const int r0 = blockIdx.x*4, e = blockIdx.y*64 + lane;
  for (int i = tid; i < 4*128; i += 256)
    reinterpret_cast<float4*>(Xs[i>>7])[i&127] =
      reinterpret_cast<const float4*>(X + (size_t)(r0+(i>>7))*512)[i&127];
  __syncthreads();
  float acc[4] = {0,0,0,0};
  const float* wp = WT + (size_t)(w*128)*512 + blockIdx.y*64 + lane;
  #pragma unroll 2
  for (int c = 0; c < 128; c += 4){
    float w0 = wp[0], w1 = wp[512], w2 = wp[1024], w3 = wp[1536];
    wp += 2048;
    #pragma unroll
    for (int rr = 0; rr < 4; ++rr){
      float4 x = *reinterpret_cast<const float4*>(&Xs[rr][w*128+c]);
      acc[rr] += x.x*w0 + x.y*w1 + x.z*w2 + x.w*w3;
    }
  }
  #pragma unroll
  for (int rr = 0; rr < 4; ++rr) part[w][rr][lane] = acc[rr];
  __syncthreads();
  const int rr = tid>>6;
  float v = part[0][rr][lane]+part[1][rr][lane]+part[2][rr][lane]+part[3][rr][lane];
  Y[(size_t)(r0+rr)*512 + e] = fmaxf(v + bias[e], 0.f);
}

// ---------------- AI[r][h] = PRESCALE * (img @ W_aiT)[r][h]. natural layout.
__global__ __launch_bounds__(256) void k_gemm_ai(
    const float* __restrict__ X, const float* __restrict__ WT,
    float* __restrict__ AI){
  __shared__ float Xs[4][512];
  __shared__ float part[4][4][64];
  const int tid = threadIdx.x, w = tid>>6, lane = tid&63;
  const int r0 = blockIdx.x*4;
  for (int i = tid; i < 4*128; i += 256)
    reinterpret_cast<float4*>(Xs[i>>7])[i&127] =
      reinterpret_cast<const float4*>(X + (size_t)(r0+(i>>7))*512)[i&127];
  __syncthreads();
  float acc[4] = {0,0,0,0};
  const float* wp = WT + (size_t)(w*128)*512 + blockIdx.y*64 + lane;
  #pragma unroll 2
  for (int c = 0; c < 128; c += 4){
    float w0 = wp[0], w1 = wp[512], w2 = wp[1024], w3 = wp[1536];
    wp += 2048;
    #pragma unroll
    for (int rr = 0; rr < 4; ++rr){
      float4 x = *reinterpret_cast<const float4*>(&Xs[rr][w*128+c]);
      acc[rr] += x.x*w0 + x.y*w1 + x.z*w2 + x.w*w3;
    }
  }
  #pragma unroll
  for (int rr = 0; rr < 4; ++rr) part[w][rr][lane] = acc[rr];
  __syncthreads();
  const int rr = tid>>6;
  float v = (part[0][rr][lane]+part[1][rr][lane]+part[2][rr][lane]+part[3][rr][lane]) * PRESCALE;
  AI[(size_t)(r0+rr)*512 + blockIdx.y*64 + lane] = v;
}

// ---------------- AWT[h][t] = PRESCALE*(E @ W_awT + b)[t][h]; out[:,512:] = E.
// grid(128,8), 256 thr, 8 tokens/block.
__global__ __launch_bounds__(256) void k_gemm_aw(
    const int* __restrict__ question, const float* __restrict__ emb,
    const float* __restrict__ WT, const float* __restrict__ bias,
    float* __restrict__ AWT, float* __restrict__ out){
  __shared__ float Es[8][512];
  __shared__ float part[4][8][64];
  const int tid = threadIdx.x, w = tid>>6, lane = tid&63;
  const int t0 = blockIdx.x*8, hb = blockIdx.y*64;
  {
    const int m = tid>>5, cb = tid&31;
    const float* er = emb + (size_t)question[t0+m]*512;
    float* orow = out + (size_t)(t0+m)*1024 + 512;
    #pragma unroll
    for (int p = 0; p < 4; ++p){
      const int cq = cb + p*32;
      float4 v = reinterpret_cast<const float4*>(er)[cq];
      reinterpret_cast<float4*>(Es[m])[cq] = v;
      if (blockIdx.y == 0) reinterpret_cast<float4*>(orow)[cq] = v;
    }
  }
  __syncthreads();
  float acc[8] = {0,0,0,0,0,0,0,0};
  const float* wp = WT + (size_t)(w*128)*512 + hb + lane;
  for (int c = 0; c < 128; c += 4){
    float w0 = wp[0], w1 = wp[512], w2 = wp[1024], w3 = wp[1536];
    wp += 2048;
    #pragma unroll
    for (int m = 0; m < 8; ++m){
      float4 x = *reinterpret_cast<const float4*>(&Es[m][w*128+c]);
      acc[m] += x.x*w0 + x.y*w1 + x.z*w2 + x.w*w3;
    }
  }
  #pragma unroll
  for (int m = 0; m < 8; ++m) part[w][m][lane] = acc[m];
  __syncthreads();
  const int m0 = tid>>6, h = hb + lane;
  const float pb = bias[h];
  #pragma unroll
  for (int k = 0; k < 2; ++k){
    const int m = m0 + k*4;
    float v = part[0][m][lane]+part[1][m][lane]+part[2][m][lane]+part[3][m][lane];
    AWT[(size_t)h*1024 + t0 + m] = (v + pb) * PRESCALE;   // transposed scatter (small)
  }
}

// ---------------- ST[r][t] = sum_h w[h] * rcp(exp2(AI'[r][h]+AWT'[h][t]) + 1)
// softmax(score) == softmax(-2*ST). grid(98,4), 256 thr.
// lane<->token (all 64 active); AI rows + w_att are wave-uniform scalar streams;
// one AWT load feeds both r-rows (r, r+98).
__global__ __launch_bounds__(256) void k_score(
    const float* __restrict__ AI, const float* __restrict__ AWT,
    const float* __restrict__ w_att, float* __restrict__ ST){
  const int rp = blockIdx.x;                       // 0..97
  const int t  = blockIdx.y*256 + threadIdx.x;     // token
  const float* __restrict__ a0 = AI + (size_t)rp*512;
  const float* __restrict__ a1 = AI + (size_t)(rp+98)*512;
  const float* __restrict__ ap = AWT + t;
  float s0 = 0.f, s1 = 0.f;
  #pragma unroll 8
  for (int h = 0; h < 512; ++h){
    const float aw = ap[(size_t)h*1024];
    const float w  = w_att[h];
    s0 += w * RCP(EXP2(a0[h] + aw) + 1.f);
    s1 += w * RCP(EXP2(a1[h] + aw) + 1.f);
  }
  ST[(size_t)rp*1024 + t]      = s0;
  ST[(size_t)(rp+98)*1024 + t] = s1;
}

// ---------------- softmax(-2*ST) (folding /196) then ctx = w @ img.
// grid(64,8): 16 tokens x 64 e per block, 256 thr.
__global__ __launch_bounds__(256) void k_ctx(
    const float* __restrict__ ST, const float* __restrict__ img,
    float* __restrict__ out){
  __shared__ float wgt[R_N][16];
  __shared__ float red[16][16];
  const int tid = threadIdx.x;
  const int t0 = blockIdx.x*16, e0 = blockIdx.y*64;
  const int rs = tid>>4, tl = tid&15;

  // pass 1: min over r (max logit = -2*min S)
  float m = 1e30f;
  for (int k = 0; k < 13; ++k){
    const int r = rs + 16*k;
    if (r < R_N) m = fminf(m, ST[(size_t)r*1024 + t0 + tl]);
  }
  red[rs][tl] = m;
  __syncthreads();
  if (tid < 16){
    float mm = red[0][tid];
    #pragma unroll
    for (int i = 1; i < 16; ++i) mm = fminf(mm, red[i][tid]);
    red[0][tid] = mm;
  }
  __syncthreads();
  const float mt = red[0][tl];
  // pass 2: p = exp(-2*(v-m)) = exp2(PRESCALE*(m-v)); row sums
  float sum = 0.f;
  for (int k = 0; k < 13; ++k){
    const int r = rs + 16*k;
    if (r < R_N){
      float p = EXP2(PRESCALE*(mt - ST[(size_t)r*1024 + t0 + tl]));
      wgt[r][tl] = p;
      sum += p;
    }
  }
  __syncthreads();
  red[rs][tl] = sum;
  __syncthreads();
  if (tid < 16){
    float ss = 0.f;
    #pragma unroll
    for (int i = 0; i < 16; ++i) ss += red[i][tid];
    red[0][tid] = 1.f / (ss * 196.f);
  }
  __syncthreads();
  const float inv = red[0][tl];
  for (int k = 0; k < 13; ++k){
    const int r = rs + 16*k;
    if (r < R_N) wgt[r][tl] *= inv;
  }
  __syncthreads();

  // phase B: ctx. wave <-> 4 tokens, lane <-> e. wgt reads are LDS broadcasts.
  const int e = e0 + (tid & 63), tq = tid >> 6;
  float acc[4] = {0.f, 0.f, 0.f, 0.f};
  const float* ip = img + e;
  #pragma unroll 4
  for (int r = 0; r < R_N; ++r){
    const float f = ip[(size_t)r*512];
    float4 w4 = *reinterpret_cast<const float4*>(&wgt[r][tq*4]);
    acc[0] += w4.x*f; acc[1] += w4.y*f; acc[2] += w4.z*f; acc[3] += w4.w*f;
  }
  #pragma unroll
  for (int j = 0; j < 4; ++j)
    out[(size_t)(t0 + tq*4 + j)*1024 + e] = acc[j];
}

extern "C" void kernel_launch(void* const* d_in, const int* in_sizes, int n_in,
                              void* d_out, int out_size, void* d_ws, size_t ws_size,
                              hipStream_t stream) {
  const int*   question = (const int*)d_in[0];
  const float* img_feat = (const float*)d_in[1];
  const float* emb      = (const float*)d_in[2];
  const float* W_img    = (const float*)d_in[3];
  const float* b_img    = (const float*)d_in[4];
  const float* W_ai     = (const float*)d_in[5];
  const float* W_aw     = (const float*)d_in[6];
  const float* b_aw     = (const float*)d_in[7];
  const float* w_att    = (const float*)d_in[8];
  // d_in[9] = b_att: constant pre-softmax shift -> cancels. Sum(w_att) term also cancels.
  float* out = (float*)d_out;

  char* ws = (char*)d_ws;
  float* WT3 = (float*)ws;                      // 3 MB (img, ai, aw transposed)
  float* img = (float*)(ws + 3145728);          // 401408 B
  float* AI  = (float*)(ws + 3547136);          // 401408 B
  float* AWT = (float*)(ws + 3948544);          // 2 MB
  float* ST  = (float*)ws;                      // 802816 B, overlays WT3 (dead after gemms)

  hipLaunchKernelGGL(k_trans3,   dim3(8,8,3),  dim3(256), 0, stream, W_img, W_ai, W_aw, WT3);
  hipLaunchKernelGGL(k_gemm_img, dim3(49,8),   dim3(256), 0, stream, img_feat, WT3, b_img, img);
  hipLaunchKernelGGL(k_gemm_ai,  dim3(49,8),   dim3(256), 0, stream, img, WT3 + 512*512, AI);
  hipLaunchKernelGGL(k_gemm_aw,  dim3(128,8),  dim3(256), 0, stream, question, emb, WT3 + 2*512*512, b_aw, AWT, out);
  hipLaunchKernelGGL(k_score,    dim3(98,4),   dim3(256), 0, stream, AI, AWT, w_att, ST);
  hipLaunchKernelGGL(k_ctx,      dim3(64,8),   dim3(256), 0, stream, ST, img, out);
}